// Round 3
// baseline (822.805 us; speedup 1.0000x reference)
//
#include <hip/hip_runtime.h>
#include <hip/hip_bf16.h>
#include <stdint.h>

#define T 2048
#define H 1024
#define NH 16
#define NKV 4
#define HD 64
#define NE 8
#define FF 2048
#define QKVD 1536

typedef unsigned short u16;
typedef short bf16x8 __attribute__((ext_vector_type(8)));
typedef float f32x4 __attribute__((ext_vector_type(4)));

__device__ __forceinline__ float bf2f(u16 u) { return __uint_as_float(((unsigned)u) << 16); }
__device__ __forceinline__ u16 f2b(float f) {
    unsigned u = __float_as_uint(f);
    unsigned r = (u + 0x7FFFu + ((u >> 16) & 1u)) >> 16;
    return (u16)r;
}

#define MFMA(a, b, c) __builtin_amdgcn_mfma_f32_16x16x32_bf16(a, b, c, 0, 0, 0)

// ---------------- f32 -> bf16 convert (n multiple of 2048) ----------------
__global__ __launch_bounds__(256) void k_cvt(const float* __restrict__ src,
                                             u16* __restrict__ dst) {
    size_t i = ((size_t)blockIdx.x * 256 + threadIdx.x) * 8;
    float4 a = *(const float4*)(src + i);
    float4 b = *(const float4*)(src + i + 4);
    bf16x8 o;
    o[0] = (short)f2b(a.x); o[1] = (short)f2b(a.y);
    o[2] = (short)f2b(a.z); o[3] = (short)f2b(a.w);
    o[4] = (short)f2b(b.x); o[5] = (short)f2b(b.y);
    o[6] = (short)f2b(b.z); o[7] = (short)f2b(b.w);
    *(bf16x8*)(dst + i) = o;
}

// ---------------- rmsnorm (f32 in, bf16 out) ----------------
__global__ __launch_bounds__(256) void k_rmsnorm(const float* __restrict__ x,
                                                 const float* __restrict__ w,
                                                 u16* __restrict__ out) {
    int t = blockIdx.x;
    const float* xr = x + (size_t)t * H;
    int base = threadIdx.x * 4;
    float v[4]; float ss = 0.f;
#pragma unroll
    for (int i = 0; i < 4; i++) { v[i] = xr[base + i]; ss += v[i] * v[i]; }
#pragma unroll
    for (int off = 32; off; off >>= 1) ss += __shfl_xor(ss, off, 64);
    __shared__ float red[4];
    int wv = threadIdx.x >> 6, lane = threadIdx.x & 63;
    if (lane == 0) red[wv] = ss;
    __syncthreads();
    float tot = red[0] + red[1] + red[2] + red[3];
    float s = rsqrtf(tot * (1.0f / H) + 1e-5f);
    u16* orow = out + (size_t)t * H;
#pragma unroll
    for (int i = 0; i < 4; i++) orow[base + i] = f2b(v[i] * s * w[base + i]);
}

// ---------------- GEMM: qkv = xn_in @ w_qkv^T  (M=2048,N=1536,K=1024, C f32) ----------------
__global__ __launch_bounds__(256) void k_gemm_qkv(const u16* __restrict__ A,
                                                  const u16* __restrict__ B,
                                                  float* __restrict__ C) {
    const int K = H;
    int lane = threadIdx.x & 63, wv = threadIdx.x >> 6;
    int l15 = lane & 15, quad = lane >> 4;
    int m0 = blockIdx.y * 128 + (wv >> 1) * 64;
    int n0 = blockIdx.x * 128 + (wv & 1) * 64;
    const u16* ap[4]; const u16* bp[4];
#pragma unroll
    for (int i = 0; i < 4; i++) ap[i] = A + (size_t)(m0 + i * 16 + l15) * K + quad * 8;
#pragma unroll
    for (int j = 0; j < 4; j++) bp[j] = B + (size_t)(n0 + j * 16 + l15) * K + quad * 8;
    f32x4 acc[4][4];
#pragma unroll
    for (int i = 0; i < 4; i++)
#pragma unroll
        for (int j = 0; j < 4; j++) acc[i][j] = (f32x4){0.f, 0.f, 0.f, 0.f};
    for (int k = 0; k < K; k += 32) {
        bf16x8 a[4], b[4];
#pragma unroll
        for (int i = 0; i < 4; i++) a[i] = *(const bf16x8*)(ap[i] + k);
#pragma unroll
        for (int j = 0; j < 4; j++) b[j] = *(const bf16x8*)(bp[j] + k);
#pragma unroll
        for (int i = 0; i < 4; i++)
#pragma unroll
            for (int j = 0; j < 4; j++) acc[i][j] = MFMA(a[i], b[j], acc[i][j]);
    }
#pragma unroll
    for (int i = 0; i < 4; i++) {
        int row = m0 + i * 16 + quad * 4;
#pragma unroll
        for (int j = 0; j < 4; j++) {
            int col = n0 + j * 16 + l15;
#pragma unroll
            for (int r = 0; r < 4; r++) C[(size_t)(row + r) * QKVD + col] = acc[i][j][r];
        }
    }
}

// ---------------- RoPE + repack to bf16 (V transposed) ----------------
__global__ __launch_bounds__(256) void k_rope(const int* __restrict__ positions,
                                              const float* __restrict__ qkv,
                                              u16* __restrict__ qb, u16* __restrict__ kb,
                                              u16* __restrict__ vt) {
    int t = blockIdx.x;
    float p = (float)positions[t];
    const float* base = qkv + (size_t)t * QKVD;
    const float kfreq = -9.210340371976184f / 32.0f;  // -ln(10000)/half
    for (int idx = threadIdx.x; idx < 512; idx += 256) {
        int hh = idx >> 5, d = idx & 31;
        float ang = p * __expf((float)d * kfreq);
        float cs = cosf(ang), sn = sinf(ang);
        float x1 = base[hh * 64 + d], x2 = base[hh * 64 + d + 32];
        qb[(size_t)t * 1024 + hh * 64 + d] = f2b(x1 * cs - x2 * sn);
        qb[(size_t)t * 1024 + hh * 64 + d + 32] = f2b(x2 * cs + x1 * sn);
    }
    if (threadIdx.x < 128) {
        int idx = threadIdx.x, kh = idx >> 5, d = idx & 31;
        float ang = p * __expf((float)d * kfreq);
        float cs = cosf(ang), sn = sinf(ang);
        const float* kin = base + 1024;
        float x1 = kin[kh * 64 + d], x2 = kin[kh * 64 + d + 32];
        kb[((size_t)t * NKV + kh) * 64 + d] = f2b(x1 * cs - x2 * sn);
        kb[((size_t)t * NKV + kh) * 64 + d + 32] = f2b(x2 * cs + x1 * sn);
    }
    {
        int idx = threadIdx.x;
        vt[(size_t)idx * T + t] = f2b(base[1280 + idx]);
    }
}

// ---------------- flash attention (causal, GQA 4:1) ----------------
__global__ __launch_bounds__(256) void k_attn(const u16* __restrict__ qb,
                                              const u16* __restrict__ kb,
                                              const u16* __restrict__ vt,
                                              u16* __restrict__ o) {
    int h = blockIdx.y;
    int q0 = blockIdx.x * 64;
    int kh = h >> 2;
    int wv = threadIdx.x >> 6, lane = threadIdx.x & 63;
    int l15 = lane & 15, quad = lane >> 4;
    int qw = q0 + wv * 16;
    __shared__ __align__(16) u16 pl[4][16 * 32];

    const u16* qrow = qb + (size_t)(qw + l15) * 1024 + h * 64 + quad * 8;
    bf16x8 aq0 = *(const bf16x8*)qrow;
    bf16x8 aq1 = *(const bf16x8*)(qrow + 32);

    f32x4 oacc[4];
#pragma unroll
    for (int c = 0; c < 4; c++) oacc[c] = (f32x4){0.f, 0.f, 0.f, 0.f};
    float mi[4], li[4];
#pragma unroll
    for (int r = 0; r < 4; r++) { mi[r] = -3e38f; li[r] = 0.f; }

    int ntiles = (q0 >> 5) + 2;
    for (int ti = 0; ti < ntiles; ++ti) {
        int kv0 = ti * 32;
        const u16* kr = kb + (size_t)((kv0 + l15) * NKV + kh) * 64 + quad * 8;
        f32x4 sA = (f32x4){0.f, 0.f, 0.f, 0.f}, sB = (f32x4){0.f, 0.f, 0.f, 0.f};
        sA = MFMA(aq0, *(const bf16x8*)kr, sA);
        sA = MFMA(aq1, *(const bf16x8*)(kr + 32), sA);
        const u16* kr2 = kr + 16 * NKV * 64;
        sB = MFMA(aq0, *(const bf16x8*)kr2, sB);
        sB = MFMA(aq1, *(const bf16x8*)(kr2 + 32), sB);
        int cA = kv0 + l15, cB = cA + 16;
#pragma unroll
        for (int r = 0; r < 4; r++) {
            int qi = qw + quad * 4 + r;
            float a = (cA <= qi) ? sA[r] * 0.125f : -3e38f;
            float b = (cB <= qi) ? sB[r] * 0.125f : -3e38f;
            float mx = fmaxf(a, b);
#pragma unroll
            for (int off = 1; off < 16; off <<= 1) mx = fmaxf(mx, __shfl_xor(mx, off, 64));
            float mn = fmaxf(mi[r], mx);
            float alpha = __expf(mi[r] - mn);
            float pa = __expf(a - mn), pb = __expf(b - mn);
            float ps = pa + pb;
#pragma unroll
            for (int off = 1; off < 16; off <<= 1) ps += __shfl_xor(ps, off, 64);
            li[r] = li[r] * alpha + ps;
            mi[r] = mn;
#pragma unroll
            for (int c = 0; c < 4; c++) oacc[c][r] = oacc[c][r] * alpha;
            int prow = quad * 4 + r;
            pl[wv][prow * 32 + l15] = f2b(pa);
            pl[wv][prow * 32 + 16 + l15] = f2b(pb);
        }
        __syncthreads();
        bf16x8 pfrag = *(const bf16x8*)&pl[wv][l15 * 32 + quad * 8];
#pragma unroll
        for (int c = 0; c < 4; c++) {
            const u16* vr = vt + (size_t)(kh * 64 + c * 16 + l15) * T + kv0 + quad * 8;
            oacc[c] = MFMA(pfrag, *(const bf16x8*)vr, oacc[c]);
        }
        __syncthreads();
    }
#pragma unroll
    for (int r = 0; r < 4; r++) {
        float inv = 1.0f / li[r];
        int row = qw + quad * 4 + r;
#pragma unroll
        for (int c = 0; c < 4; c++)
            o[(size_t)row * 1024 + h * 64 + c * 16 + l15] = f2b(oacc[c][r] * inv);
    }
}

// ---------------- GEMM: x1 = hidden + o @ w_o^T (M=2048,N=1024,K=1024) ----------------
__global__ __launch_bounds__(256) void k_gemm_wo(const u16* __restrict__ A,
                                                 const u16* __restrict__ B,
                                                 const float* __restrict__ hid,
                                                 float* __restrict__ x1) {
    const int K = H;
    int lane = threadIdx.x & 63, wv = threadIdx.x >> 6;
    int l15 = lane & 15, quad = lane >> 4;
    int m0 = blockIdx.y * 128 + (wv >> 1) * 64;
    int n0 = blockIdx.x * 128 + (wv & 1) * 64;
    const u16* ap[4]; const u16* bp[4];
#pragma unroll
    for (int i = 0; i < 4; i++) ap[i] = A + (size_t)(m0 + i * 16 + l15) * K + quad * 8;
#pragma unroll
    for (int j = 0; j < 4; j++) bp[j] = B + (size_t)(n0 + j * 16 + l15) * K + quad * 8;
    f32x4 acc[4][4];
#pragma unroll
    for (int i = 0; i < 4; i++)
#pragma unroll
        for (int j = 0; j < 4; j++) acc[i][j] = (f32x4){0.f, 0.f, 0.f, 0.f};
    for (int k = 0; k < K; k += 32) {
        bf16x8 a[4], b[4];
#pragma unroll
        for (int i = 0; i < 4; i++) a[i] = *(const bf16x8*)(ap[i] + k);
#pragma unroll
        for (int j = 0; j < 4; j++) b[j] = *(const bf16x8*)(bp[j] + k);
#pragma unroll
        for (int i = 0; i < 4; i++)
#pragma unroll
            for (int j = 0; j < 4; j++) acc[i][j] = MFMA(a[i], b[j], acc[i][j]);
    }
#pragma unroll
    for (int i = 0; i < 4; i++) {
        int row = m0 + i * 16 + quad * 4;
#pragma unroll
        for (int j = 0; j < 4; j++) {
            int col = n0 + j * 16 + l15;
#pragma unroll
            for (int r = 0; r < 4; r++) {
                size_t idx = (size_t)(row + r) * H + col;
                x1[idx] = hid[idx] + acc[i][j][r];
            }
        }
    }
}

// ---------------- MoE routing (full f32: matches np reference) ----------------
__global__ void k_zero(int* cnt) { if (threadIdx.x < NE) cnt[threadIdx.x] = 0; }

__global__ __launch_bounds__(256) void k_route(const float* __restrict__ x1,
                                               const float* __restrict__ wpost,
                                               const float* __restrict__ gw,
                                               int* cnt, int* ids, int* rank,
                                               float* gwt) {
    int wv = threadIdx.x >> 6, lane = threadIdx.x & 63;
    int t = blockIdx.x * 4 + wv;
    const float* xr = x1 + (size_t)t * H + lane * 16;
    float pv[16];
    float ss = 0.f;
#pragma unroll
    for (int i = 0; i < 16; i++) { float v = xr[i]; pv[i] = v; ss += v * v; }
#pragma unroll
    for (int off = 32; off; off >>= 1) ss += __shfl_xor(ss, off, 64);
    float s = rsqrtf(ss * (1.0f / H) + 1e-5f);
#pragma unroll
    for (int i = 0; i < 16; i++) pv[i] *= wpost[lane * 16 + i];
    float lg[NE];
#pragma unroll
    for (int e = 0; e < NE; e++) {
        const float* gr = gw + (size_t)e * H + lane * 16;
        float d = 0.f;
#pragma unroll
        for (int i = 0; i < 16; i++) d += pv[i] * gr[i];
#pragma unroll
        for (int off = 32; off; off >>= 1) d += __shfl_xor(d, off, 64);
        lg[e] = d * s;
    }
    if (lane == 0) {
        int i0 = 0; float b0 = lg[0];
        for (int e = 1; e < NE; e++) if (lg[e] > b0) { b0 = lg[e]; i0 = e; }
        int i1 = (i0 == 0) ? 1 : 0; float b1 = lg[i1];
        for (int e = 0; e < NE; e++)
            if (e != i0 && lg[e] > b1) { b1 = lg[e]; i1 = e; }
        float g0 = 1.0f / (1.0f + __expf(b1 - b0));
        float g1 = 1.0f - g0;
        int r0 = atomicAdd(&cnt[i0], 1);
        int r1 = atomicAdd(&cnt[i1], 1);
        ids[2 * t] = i0; ids[2 * t + 1] = i1;
        rank[2 * t] = r0; rank[2 * t + 1] = r1;
        gwt[2 * t] = g0; gwt[2 * t + 1] = g1;
    }
}

__global__ void k_prefix(const int* cnt, int* offs) {
    if (threadIdx.x == 0) {
        int a = 0;
        for (int e = 0; e < NE; e++) { offs[e] = a; a += cnt[e]; }
    }
}

__global__ __launch_bounds__(256) void k_scatter(const int* __restrict__ ids,
                                                 const int* __restrict__ rank,
                                                 const int* __restrict__ offs,
                                                 int* __restrict__ list,
                                                 int* __restrict__ slotof) {
    int t = blockIdx.x * 256 + threadIdx.x;
#pragma unroll
    for (int j = 0; j < 2; j++) {
        int e = ids[2 * t + j];
        int s = offs[e] + rank[2 * t + j];
        list[s] = t;
        slotof[2 * t + j] = s;
    }
}

// ---------------- expert GEMM1: act = silu(x@w1^T) * (x@w3^T), gathered rows ----------------
__global__ __launch_bounds__(256, 2) void k_gemm1(const u16* __restrict__ xnp,
                                                  const u16* __restrict__ w1,
                                                  const u16* __restrict__ w3,
                                                  const int* __restrict__ cnt,
                                                  const int* __restrict__ offs,
                                                  const int* __restrict__ list,
                                                  u16* __restrict__ act) {
    int e = blockIdx.z;
    int ce = cnt[e], oe = offs[e];
    if ((int)blockIdx.y * 128 >= ce) return;
    const int K = H;
    int lane = threadIdx.x & 63, wv = threadIdx.x >> 6;
    int l15 = lane & 15, quad = lane >> 4;
    int m0 = blockIdx.y * 128 + (wv >> 1) * 64;
    int n0 = blockIdx.x * 128 + (wv & 1) * 64;
    const u16* ap[4];
#pragma unroll
    for (int i = 0; i < 4; i++) {
        int r = m0 + i * 16 + l15;
        int sl = oe + min(r, ce - 1);
        int tok = list[sl];
        ap[i] = xnp + (size_t)tok * K + quad * 8;
    }
    const u16* B1 = w1 + (size_t)e * FF * H;
    const u16* B3 = w3 + (size_t)e * FF * H;
    const u16* b1p[4]; const u16* b3p[4];
#pragma unroll
    for (int j = 0; j < 4; j++) {
        size_t ro = (size_t)(n0 + j * 16 + l15) * K + quad * 8;
        b1p[j] = B1 + ro; b3p[j] = B3 + ro;
    }
    f32x4 a1[4][4], a3[4][4];
#pragma unroll
    for (int i = 0; i < 4; i++)
#pragma unroll
        for (int j = 0; j < 4; j++) {
            a1[i][j] = (f32x4){0.f, 0.f, 0.f, 0.f};
            a3[i][j] = (f32x4){0.f, 0.f, 0.f, 0.f};
        }
    for (int k = 0; k < K; k += 32) {
        bf16x8 a[4], b1v[4], b3v[4];
#pragma unroll
        for (int i = 0; i < 4; i++) a[i] = *(const bf16x8*)(ap[i] + k);
#pragma unroll
        for (int j = 0; j < 4; j++) { b1v[j] = *(const bf16x8*)(b1p[j] + k); b3v[j] = *(const bf16x8*)(b3p[j] + k); }
#pragma unroll
        for (int i = 0; i < 4; i++)
#pragma unroll
            for (int j = 0; j < 4; j++) {
                a1[i][j] = MFMA(a[i], b1v[j], a1[i][j]);
                a3[i][j] = MFMA(a[i], b3v[j], a3[i][j]);
            }
    }
#pragma unroll
    for (int i = 0; i < 4; i++) {
        int rb = m0 + i * 16 + quad * 4;
#pragma unroll
        for (int r = 0; r < 4; r++) {
            int row = rb + r;
            if (row < ce) {
#pragma unroll
                for (int j = 0; j < 4; j++) {
                    int col = n0 + j * 16 + l15;
                    float h1 = a1[i][j][r], h3 = a3[i][j][r];
                    float sv = h1 / (1.0f + __expf(-h1));
                    act[(size_t)(oe + row) * FF + col] = f2b(sv * h3);
                }
            }
        }
    }
}

// ---------------- expert GEMM2: y = act @ w2^T (slot rows, K=2048,N=1024) ----------------
__global__ __launch_bounds__(256) void k_gemm2(const u16* __restrict__ act,
                                               const u16* __restrict__ w2,
                                               const int* __restrict__ cnt,
                                               const int* __restrict__ offs,
                                               float* __restrict__ y) {
    int e = blockIdx.z;
    int ce = cnt[e], oe = offs[e];
    if ((int)blockIdx.y * 128 >= ce) return;
    const int K = FF;
    int lane = threadIdx.x & 63, wv = threadIdx.x >> 6;
    int l15 = lane & 15, quad = lane >> 4;
    int m0 = blockIdx.y * 128 + (wv >> 1) * 64;
    int n0 = blockIdx.x * 128 + (wv & 1) * 64;
    const u16* ap[4]; const u16* bp[4];
#pragma unroll
    for (int i = 0; i < 4; i++) {
        int r = min(m0 + i * 16 + l15, ce - 1);
        ap[i] = act + (size_t)(oe + r) * K + quad * 8;
    }
    const u16* B = w2 + (size_t)e * H * FF;
#pragma unroll
    for (int j = 0; j < 4; j++) bp[j] = B + (size_t)(n0 + j * 16 + l15) * K + quad * 8;
    f32x4 acc[4][4];
#pragma unroll
    for (int i = 0; i < 4; i++)
#pragma unroll
        for (int j = 0; j < 4; j++) acc[i][j] = (f32x4){0.f, 0.f, 0.f, 0.f};
    for (int k = 0; k < K; k += 32) {
        bf16x8 a[4], b[4];
#pragma unroll
        for (int i = 0; i < 4; i++) a[i] = *(const bf16x8*)(ap[i] + k);
#pragma unroll
        for (int j = 0; j < 4; j++) b[j] = *(const bf16x8*)(bp[j] + k);
#pragma unroll
        for (int i = 0; i < 4; i++)
#pragma unroll
            for (int j = 0; j < 4; j++) acc[i][j] = MFMA(a[i], b[j], acc[i][j]);
    }
#pragma unroll
    for (int i = 0; i < 4; i++) {
        int rb = m0 + i * 16 + quad * 4;
#pragma unroll
        for (int r = 0; r < 4; r++) {
            int row = rb + r;
            if (row < ce) {
#pragma unroll
                for (int j = 0; j < 4; j++) {
                    int col = n0 + j * 16 + l15;
                    y[(size_t)(oe + row) * H + col] = acc[i][j][r];
                }
            }
        }
    }
}

// ---------------- combine + final rmsnorm, write both outputs (f32) ----------------
__global__ __launch_bounds__(256) void k_combine(const float* __restrict__ x1,
                                                 const float* __restrict__ y,
                                                 const int* __restrict__ slotof,
                                                 const float* __restrict__ gwt,
                                                 const float* __restrict__ wnext,
                                                 float* __restrict__ dout) {
    int t = blockIdx.x;
    int s0 = slotof[2 * t], s1 = slotof[2 * t + 1];
    float g0 = gwt[2 * t], g1 = gwt[2 * t + 1];
    int base = threadIdx.x * 4;
    float v[4]; float ss = 0.f;
#pragma unroll
    for (int i = 0; i < 4; i++) {
        int idx = base + i;
        float val = x1[(size_t)t * H + idx] + g0 * y[(size_t)s0 * H + idx] + g1 * y[(size_t)s1 * H + idx];
        v[i] = val; ss += val * val;
    }
#pragma unroll
    for (int off = 32; off; off >>= 1) ss += __shfl_xor(ss, off, 64);
    __shared__ float red[4];
    int wv = threadIdx.x >> 6, lane = threadIdx.x & 63;
    if (lane == 0) red[wv] = ss;
    __syncthreads();
    float tot = red[0] + red[1] + red[2] + red[3];
    float s = rsqrtf(tot * (1.0f / H) + 1e-5f);
#pragma unroll
    for (int i = 0; i < 4; i++) {
        int idx = base + i;
        dout[(size_t)t * H + idx] = v[i] * s * wnext[idx];
        dout[(size_t)T * H + (size_t)t * H + idx] = v[i];
    }
}

extern "C" void kernel_launch(void* const* d_in, const int* in_sizes, int n_in,
                              void* d_out, int out_size, void* d_ws, size_t ws_size,
                              hipStream_t stream) {
    (void)in_sizes; (void)n_in; (void)out_size; (void)ws_size;
    const int*   positions = (const int*)d_in[0];
    const float* hidden    = (const float*)d_in[1];
    const float* w_qkv     = (const float*)d_in[2];
    const float* w_o       = (const float*)d_in[3];
    const float* norm_in   = (const float*)d_in[4];
    const float* norm_post = (const float*)d_in[5];
    const float* norm_next = (const float*)d_in[6];
    const float* gate_w    = (const float*)d_in[7];
    const float* w1        = (const float*)d_in[8];
    const float* w2        = (const float*)d_in[9];
    const float* w3        = (const float*)d_in[10];

    char* ws = (char*)d_ws;
    const size_t MB = (size_t)1 << 20;
    u16*   wqb  = (u16*)(ws + 0 * MB);     // 3 MB  [0,3)
    u16*   wob  = (u16*)(ws + 3 * MB);     // 2 MB  [3,5)
    u16*   w1b  = (u16*)(ws + 5 * MB);     // 32 MB [5,37)
    u16*   w2b  = (u16*)(ws + 37 * MB);    // 32 MB [37,69)
    u16*   w3b  = (u16*)(ws + 69 * MB);    // 32 MB [69,101)
    u16*   xn_in= (u16*)(ws + 101 * MB);   // 4 MB  [101,105)
    float* qkv  = (float*)(ws + 105 * MB); // 12 MB [105,117) (dead after rope)
    u16*   qb   = (u16*)(ws + 117 * MB);   // 4 MB  [117,121)
    u16*   kbuf = (u16*)(ws + 121 * MB);   // 1 MB
    u16*   vt   = (u16*)(ws + 122 * MB);   // 1 MB
    u16*   obuf = (u16*)(ws + 123 * MB);   // 4 MB  [123,127)
    float* x1   = (float*)(ws + 127 * MB); // 8 MB  [127,135) live to end
    u16*   xnp  = (u16*)(ws + 101 * MB);   // reuse xn_in slot [101,105)
    u16*   act  = (u16*)(ws + 105 * MB);   // 16 MB reuse qkv/qb [105,121)
    float* yb   = (float*)(ws + 135 * MB); // 16 MB [135,151)
    char*  rt   = ws + 151 * MB;
    int*   cnt    = (int*)(rt);
    int*   offs   = (int*)(rt + 64);
    int*   ids    = (int*)(rt + 128);
    int*   rank   = (int*)(rt + 128 + 16384);
    float* gwt    = (float*)(rt + 128 + 2 * 16384);
    int*   slotof = (int*)(rt + 128 + 3 * 16384);
    int*   list   = (int*)(rt + 128 + 4 * 16384);
    float* dout   = (float*)d_out;

    // weight conversion f32 -> bf16 (each size divisible by 2048)
    k_cvt<<<dim3(QKVD * H / 2048), dim3(256), 0, stream>>>(w_qkv, wqb);
    k_cvt<<<dim3(H * H / 2048), dim3(256), 0, stream>>>(w_o, wob);
    k_cvt<<<dim3(NE * FF * H / 2048), dim3(256), 0, stream>>>(w1, w1b);
    k_cvt<<<dim3(NE * H * FF / 2048), dim3(256), 0, stream>>>(w2, w2b);
    k_cvt<<<dim3(NE * FF * H / 2048), dim3(256), 0, stream>>>(w3, w3b);

    k_rmsnorm<<<dim3(T), dim3(256), 0, stream>>>(hidden, norm_in, xn_in);
    k_gemm_qkv<<<dim3(QKVD / 128, T / 128), dim3(256), 0, stream>>>(xn_in, wqb, qkv);
    k_rope<<<dim3(T), dim3(256), 0, stream>>>(positions, qkv, qb, kbuf, vt);
    k_attn<<<dim3(T / 64, NH), dim3(256), 0, stream>>>(qb, kbuf, vt, obuf);
    k_gemm_wo<<<dim3(H / 128, T / 128), dim3(256), 0, stream>>>(obuf, wob, hidden, x1);
    k_rmsnorm<<<dim3(T), dim3(256), 0, stream>>>(x1, norm_post, xnp);
    k_zero<<<dim3(1), dim3(64), 0, stream>>>(cnt);
    k_route<<<dim3(T / 4), dim3(256), 0, stream>>>(x1, norm_post, gate_w, cnt, ids, rank, gwt);
    k_prefix<<<dim3(1), dim3(1), 0, stream>>>(cnt, offs);
    k_scatter<<<dim3(T / 256), dim3(256), 0, stream>>>(ids, rank, offs, list, slotof);
    k_gemm1<<<dim3(FF / 128, T / 128, NE), dim3(256), 0, stream>>>(xnp, w1b, w3b, cnt, offs, list, act);
    k_gemm2<<<dim3(H / 128, T / 128, NE), dim3(256), 0, stream>>>(act, w2b, cnt, offs, yb);
    k_combine<<<dim3(T), dim3(256), 0, stream>>>(x1, yb, slotof, gwt, norm_next, dout);
}

// Round 4
// 633.142 us; speedup vs baseline: 1.2996x; 1.2996x over previous
//
#include <hip/hip_runtime.h>
#include <hip/hip_bf16.h>
#include <stdint.h>

#define T 2048
#define H 1024
#define NH 16
#define NKV 4
#define HD 64
#define NE 8
#define FF 2048
#define QKVD 1536

typedef unsigned short u16;
typedef short bf16x8 __attribute__((ext_vector_type(8)));
typedef float f32x4 __attribute__((ext_vector_type(4)));

__device__ __forceinline__ float bf2f(u16 u) { return __uint_as_float(((unsigned)u) << 16); }
__device__ __forceinline__ u16 f2b(float f) {
    unsigned u = __float_as_uint(f);
    unsigned r = (u + 0x7FFFu + ((u >> 16) & 1u)) >> 16;
    return (u16)r;
}

#define MFMA(a, b, c) __builtin_amdgcn_mfma_f32_16x16x32_bf16(a, b, c, 0, 0, 0)

// async global->LDS, 16B per lane; LDS dest = wave-uniform base + lane*16
__device__ __forceinline__ void gll16(const u16* g, u16* l) {
    __builtin_amdgcn_global_load_lds(
        (const __attribute__((address_space(1))) void*)g,
        (__attribute__((address_space(3))) void*)l, 16, 0, 0);
}

// ---------------- f32 -> bf16 convert (n multiple of 2048) ----------------
__global__ __launch_bounds__(256) void k_cvt(const float* __restrict__ src,
                                             u16* __restrict__ dst) {
    size_t i = ((size_t)blockIdx.x * 256 + threadIdx.x) * 8;
    float4 a = *(const float4*)(src + i);
    float4 b = *(const float4*)(src + i + 4);
    bf16x8 o;
    o[0] = (short)f2b(a.x); o[1] = (short)f2b(a.y);
    o[2] = (short)f2b(a.z); o[3] = (short)f2b(a.w);
    o[4] = (short)f2b(b.x); o[5] = (short)f2b(b.y);
    o[6] = (short)f2b(b.z); o[7] = (short)f2b(b.w);
    *(bf16x8*)(dst + i) = o;
}

// ---------------- rmsnorm (f32 in, bf16 out) ----------------
__global__ __launch_bounds__(256) void k_rmsnorm(const float* __restrict__ x,
                                                 const float* __restrict__ w,
                                                 u16* __restrict__ out) {
    int t = blockIdx.x;
    const float* xr = x + (size_t)t * H;
    int base = threadIdx.x * 4;
    float v[4]; float ss = 0.f;
#pragma unroll
    for (int i = 0; i < 4; i++) { v[i] = xr[base + i]; ss += v[i] * v[i]; }
#pragma unroll
    for (int off = 32; off; off >>= 1) ss += __shfl_xor(ss, off, 64);
    __shared__ float red[4];
    int wv = threadIdx.x >> 6, lane = threadIdx.x & 63;
    if (lane == 0) red[wv] = ss;
    __syncthreads();
    float tot = red[0] + red[1] + red[2] + red[3];
    float s = rsqrtf(tot * (1.0f / H) + 1e-5f);
    u16* orow = out + (size_t)t * H;
#pragma unroll
    for (int i = 0; i < 4; i++) orow[base + i] = f2b(v[i] * s * w[base + i]);
}

// ---------------- staged GEMM: qkv = xn_in @ w_qkv^T (M=2048,N=1536,K=1024) ----------------
__global__ __launch_bounds__(256) void k_gemm_qkv(const u16* __restrict__ A,
                                                  const u16* __restrict__ B,
                                                  float* __restrict__ C) {
    __shared__ u16 As[128 * 32], Bs[128 * 32];
    const int K = H;
    int lane = threadIdx.x & 63, wv = threadIdx.x >> 6;
    int l15 = lane & 15, quad = lane >> 4;
    int gm = blockIdx.y * 128, gn = blockIdx.x * 128;
    int c0 = wv * 128 + lane, c1 = c0 + 64;
    int r0 = c0 >> 2, cc0 = (c0 & 3) * 8;
    int r1 = c1 >> 2, cc1 = (c1 & 3) * 8;
    const u16* ag0 = A + (size_t)(gm + r0) * K + cc0;
    const u16* ag1 = A + (size_t)(gm + r1) * K + cc1;
    const u16* bg0 = B + (size_t)(gn + r0) * K + cc0;
    const u16* bg1 = B + (size_t)(gn + r1) * K + cc1;
    u16* la0 = As + (size_t)(wv * 128) * 8;
    u16* la1 = As + (size_t)(wv * 128 + 64) * 8;
    u16* lb0 = Bs + (size_t)(wv * 128) * 8;
    u16* lb1 = Bs + (size_t)(wv * 128 + 64) * 8;
    int am = (wv >> 1) * 64, bn = (wv & 1) * 64;
    f32x4 acc[4][4];
#pragma unroll
    for (int i = 0; i < 4; i++)
#pragma unroll
        for (int j = 0; j < 4; j++) acc[i][j] = (f32x4){0.f, 0.f, 0.f, 0.f};
    for (int kk = 0; kk < K; kk += 32) {
        gll16(ag0 + kk, la0);
        gll16(ag1 + kk, la1);
        gll16(bg0 + kk, lb0);
        gll16(bg1 + kk, lb1);
        __syncthreads();
        bf16x8 a[4], b[4];
#pragma unroll
        for (int i = 0; i < 4; i++) a[i] = *(const bf16x8*)(As + (am + i * 16 + l15) * 32 + quad * 8);
#pragma unroll
        for (int j = 0; j < 4; j++) b[j] = *(const bf16x8*)(Bs + (bn + j * 16 + l15) * 32 + quad * 8);
#pragma unroll
        for (int i = 0; i < 4; i++)
#pragma unroll
            for (int j = 0; j < 4; j++) acc[i][j] = MFMA(a[i], b[j], acc[i][j]);
        __syncthreads();
    }
#pragma unroll
    for (int i = 0; i < 4; i++) {
        int row = gm + am + i * 16 + quad * 4;
#pragma unroll
        for (int j = 0; j < 4; j++) {
            int col = gn + bn + j * 16 + l15;
#pragma unroll
            for (int r = 0; r < 4; r++) C[(size_t)(row + r) * QKVD + col] = acc[i][j][r];
        }
    }
}

// ---------------- RoPE + repack to bf16 (V transposed) ----------------
__global__ __launch_bounds__(256) void k_rope(const int* __restrict__ positions,
                                              const float* __restrict__ qkv,
                                              u16* __restrict__ qb, u16* __restrict__ kb,
                                              u16* __restrict__ vt) {
    int t = blockIdx.x;
    float p = (float)positions[t];
    const float* base = qkv + (size_t)t * QKVD;
    const float kfreq = -9.210340371976184f / 32.0f;  // -ln(10000)/half
    for (int idx = threadIdx.x; idx < 512; idx += 256) {
        int hh = idx >> 5, d = idx & 31;
        float ang = p * __expf((float)d * kfreq);
        float cs = cosf(ang), sn = sinf(ang);
        float x1 = base[hh * 64 + d], x2 = base[hh * 64 + d + 32];
        qb[(size_t)t * 1024 + hh * 64 + d] = f2b(x1 * cs - x2 * sn);
        qb[(size_t)t * 1024 + hh * 64 + d + 32] = f2b(x2 * cs + x1 * sn);
    }
    if (threadIdx.x < 128) {
        int idx = threadIdx.x, kh = idx >> 5, d = idx & 31;
        float ang = p * __expf((float)d * kfreq);
        float cs = cosf(ang), sn = sinf(ang);
        const float* kin = base + 1024;
        float x1 = kin[kh * 64 + d], x2 = kin[kh * 64 + d + 32];
        kb[((size_t)t * NKV + kh) * 64 + d] = f2b(x1 * cs - x2 * sn);
        kb[((size_t)t * NKV + kh) * 64 + d + 32] = f2b(x2 * cs + x1 * sn);
    }
    {
        int idx = threadIdx.x;
        vt[(size_t)idx * T + t] = f2b(base[1280 + idx]);
    }
}

// ---------------- flash attention (causal, GQA 4:1) ----------------
__global__ __launch_bounds__(256) void k_attn(const u16* __restrict__ qb,
                                              const u16* __restrict__ kb,
                                              const u16* __restrict__ vt,
                                              u16* __restrict__ o) {
    int h = blockIdx.y;
    int q0 = blockIdx.x * 64;
    int kh = h >> 2;
    int wv = threadIdx.x >> 6, lane = threadIdx.x & 63;
    int l15 = lane & 15, quad = lane >> 4;
    int qw = q0 + wv * 16;
    __shared__ __align__(16) u16 pl[4][16 * 32];

    const u16* qrow = qb + (size_t)(qw + l15) * 1024 + h * 64 + quad * 8;
    bf16x8 aq0 = *(const bf16x8*)qrow;
    bf16x8 aq1 = *(const bf16x8*)(qrow + 32);

    f32x4 oacc[4];
#pragma unroll
    for (int c = 0; c < 4; c++) oacc[c] = (f32x4){0.f, 0.f, 0.f, 0.f};
    float mi[4], li[4];
#pragma unroll
    for (int r = 0; r < 4; r++) { mi[r] = -3e38f; li[r] = 0.f; }

    int ntiles = (q0 >> 5) + 2;
    for (int ti = 0; ti < ntiles; ++ti) {
        int kv0 = ti * 32;
        const u16* kr = kb + (size_t)((kv0 + l15) * NKV + kh) * 64 + quad * 8;
        f32x4 sA = (f32x4){0.f, 0.f, 0.f, 0.f}, sB = (f32x4){0.f, 0.f, 0.f, 0.f};
        sA = MFMA(aq0, *(const bf16x8*)kr, sA);
        sA = MFMA(aq1, *(const bf16x8*)(kr + 32), sA);
        const u16* kr2 = kr + 16 * NKV * 64;
        sB = MFMA(aq0, *(const bf16x8*)kr2, sB);
        sB = MFMA(aq1, *(const bf16x8*)(kr2 + 32), sB);
        int cA = kv0 + l15, cB = cA + 16;
#pragma unroll
        for (int r = 0; r < 4; r++) {
            int qi = qw + quad * 4 + r;
            float a = (cA <= qi) ? sA[r] * 0.125f : -3e38f;
            float b = (cB <= qi) ? sB[r] * 0.125f : -3e38f;
            float mx = fmaxf(a, b);
#pragma unroll
            for (int off = 1; off < 16; off <<= 1) mx = fmaxf(mx, __shfl_xor(mx, off, 64));
            float mn = fmaxf(mi[r], mx);
            float alpha = __expf(mi[r] - mn);
            float pa = __expf(a - mn), pb = __expf(b - mn);
            float ps = pa + pb;
#pragma unroll
            for (int off = 1; off < 16; off <<= 1) ps += __shfl_xor(ps, off, 64);
            li[r] = li[r] * alpha + ps;
            mi[r] = mn;
#pragma unroll
            for (int c = 0; c < 4; c++) oacc[c][r] = oacc[c][r] * alpha;
            int prow = quad * 4 + r;
            pl[wv][prow * 32 + l15] = f2b(pa);
            pl[wv][prow * 32 + 16 + l15] = f2b(pb);
        }
        __syncthreads();
        bf16x8 pfrag = *(const bf16x8*)&pl[wv][l15 * 32 + quad * 8];
#pragma unroll
        for (int c = 0; c < 4; c++) {
            const u16* vr = vt + (size_t)(kh * 64 + c * 16 + l15) * T + kv0 + quad * 8;
            oacc[c] = MFMA(pfrag, *(const bf16x8*)vr, oacc[c]);
        }
        __syncthreads();
    }
#pragma unroll
    for (int r = 0; r < 4; r++) {
        float inv = 1.0f / li[r];
        int row = qw + quad * 4 + r;
#pragma unroll
        for (int c = 0; c < 4; c++)
            o[(size_t)row * 1024 + h * 64 + c * 16 + l15] = f2b(oacc[c][r] * inv);
    }
}

// ---------------- staged GEMM: x1 = hidden + o @ w_o^T (M=2048,N=1024,K=1024) ----------------
__global__ __launch_bounds__(256) void k_gemm_wo(const u16* __restrict__ A,
                                                 const u16* __restrict__ B,
                                                 const float* __restrict__ hid,
                                                 float* __restrict__ x1) {
    __shared__ u16 As[128 * 32], Bs[128 * 32];
    const int K = H;
    int lane = threadIdx.x & 63, wv = threadIdx.x >> 6;
    int l15 = lane & 15, quad = lane >> 4;
    int gm = blockIdx.y * 128, gn = blockIdx.x * 128;
    int c0 = wv * 128 + lane, c1 = c0 + 64;
    int r0 = c0 >> 2, cc0 = (c0 & 3) * 8;
    int r1 = c1 >> 2, cc1 = (c1 & 3) * 8;
    const u16* ag0 = A + (size_t)(gm + r0) * K + cc0;
    const u16* ag1 = A + (size_t)(gm + r1) * K + cc1;
    const u16* bg0 = B + (size_t)(gn + r0) * K + cc0;
    const u16* bg1 = B + (size_t)(gn + r1) * K + cc1;
    u16* la0 = As + (size_t)(wv * 128) * 8;
    u16* la1 = As + (size_t)(wv * 128 + 64) * 8;
    u16* lb0 = Bs + (size_t)(wv * 128) * 8;
    u16* lb1 = Bs + (size_t)(wv * 128 + 64) * 8;
    int am = (wv >> 1) * 64, bn = (wv & 1) * 64;
    f32x4 acc[4][4];
#pragma unroll
    for (int i = 0; i < 4; i++)
#pragma unroll
        for (int j = 0; j < 4; j++) acc[i][j] = (f32x4){0.f, 0.f, 0.f, 0.f};
    for (int kk = 0; kk < K; kk += 32) {
        gll16(ag0 + kk, la0);
        gll16(ag1 + kk, la1);
        gll16(bg0 + kk, lb0);
        gll16(bg1 + kk, lb1);
        __syncthreads();
        bf16x8 a[4], b[4];
#pragma unroll
        for (int i = 0; i < 4; i++) a[i] = *(const bf16x8*)(As + (am + i * 16 + l15) * 32 + quad * 8);
#pragma unroll
        for (int j = 0; j < 4; j++) b[j] = *(const bf16x8*)(Bs + (bn + j * 16 + l15) * 32 + quad * 8);
#pragma unroll
        for (int i = 0; i < 4; i++)
#pragma unroll
            for (int j = 0; j < 4; j++) acc[i][j] = MFMA(a[i], b[j], acc[i][j]);
        __syncthreads();
    }
#pragma unroll
    for (int i = 0; i < 4; i++) {
        int row = gm + am + i * 16 + quad * 4;
#pragma unroll
        for (int j = 0; j < 4; j++) {
            int col = gn + bn + j * 16 + l15;
#pragma unroll
            for (int r = 0; r < 4; r++) {
                size_t idx = (size_t)(row + r) * H + col;
                x1[idx] = hid[idx] + acc[i][j][r];
            }
        }
    }
}

// ---------------- MoE routing (full f32: matches np reference) ----------------
__global__ void k_zero(int* cnt) { if (threadIdx.x < NE) cnt[threadIdx.x] = 0; }

__global__ __launch_bounds__(256) void k_route(const float* __restrict__ x1,
                                               const float* __restrict__ wpost,
                                               const float* __restrict__ gw,
                                               int* cnt, int* ids, int* rank,
                                               float* gwt) {
    int wv = threadIdx.x >> 6, lane = threadIdx.x & 63;
    int t = blockIdx.x * 4 + wv;
    const float* xr = x1 + (size_t)t * H + lane * 16;
    float pv[16];
    float ss = 0.f;
#pragma unroll
    for (int i = 0; i < 16; i++) { float v = xr[i]; pv[i] = v; ss += v * v; }
#pragma unroll
    for (int off = 32; off; off >>= 1) ss += __shfl_xor(ss, off, 64);
    float s = rsqrtf(ss * (1.0f / H) + 1e-5f);
#pragma unroll
    for (int i = 0; i < 16; i++) pv[i] *= wpost[lane * 16 + i];
    float lg[NE];
#pragma unroll
    for (int e = 0; e < NE; e++) {
        const float* gr = gw + (size_t)e * H + lane * 16;
        float d = 0.f;
#pragma unroll
        for (int i = 0; i < 16; i++) d += pv[i] * gr[i];
#pragma unroll
        for (int off = 32; off; off >>= 1) d += __shfl_xor(d, off, 64);
        lg[e] = d * s;
    }
    if (lane == 0) {
        int i0 = 0; float b0 = lg[0];
        for (int e = 1; e < NE; e++) if (lg[e] > b0) { b0 = lg[e]; i0 = e; }
        int i1 = (i0 == 0) ? 1 : 0; float b1 = lg[i1];
        for (int e = 0; e < NE; e++)
            if (e != i0 && lg[e] > b1) { b1 = lg[e]; i1 = e; }
        float g0 = 1.0f / (1.0f + __expf(b1 - b0));
        float g1 = 1.0f - g0;
        int r0 = atomicAdd(&cnt[i0], 1);
        int r1 = atomicAdd(&cnt[i1], 1);
        ids[2 * t] = i0; ids[2 * t + 1] = i1;
        rank[2 * t] = r0; rank[2 * t + 1] = r1;
        gwt[2 * t] = g0; gwt[2 * t + 1] = g1;
    }
}

__global__ void k_prefix(const int* cnt, int* offs) {
    if (threadIdx.x == 0) {
        int a = 0;
        for (int e = 0; e < NE; e++) { offs[e] = a; a += cnt[e]; }
    }
}

__global__ __launch_bounds__(256) void k_scatter(const int* __restrict__ ids,
                                                 const int* __restrict__ rank,
                                                 const int* __restrict__ offs,
                                                 int* __restrict__ list,
                                                 int* __restrict__ slotof) {
    int t = blockIdx.x * 256 + threadIdx.x;
#pragma unroll
    for (int j = 0; j < 2; j++) {
        int e = ids[2 * t + j];
        int s = offs[e] + rank[2 * t + j];
        list[s] = t;
        slotof[2 * t + j] = s;
    }
}

// ---------------- staged expert GEMM1: act = silu(x@w1^T)*(x@w3^T), gathered A ----------------
__global__ __launch_bounds__(256, 2) void k_gemm1(const u16* __restrict__ xnp,
                                                  const u16* __restrict__ w1,
                                                  const u16* __restrict__ w3,
                                                  const int* __restrict__ cnt,
                                                  const int* __restrict__ offs,
                                                  const int* __restrict__ list,
                                                  u16* __restrict__ act) {
    int e = blockIdx.z;
    int ce = cnt[e], oe = offs[e];
    int gm = blockIdx.y * 128;
    if (gm >= ce) return;
    __shared__ u16 As[128 * 32], B1s[128 * 32], B3s[128 * 32];
    const int K = H;
    int lane = threadIdx.x & 63, wv = threadIdx.x >> 6;
    int l15 = lane & 15, quad = lane >> 4;
    int gn = blockIdx.x * 128;
    int c0 = wv * 128 + lane, c1 = c0 + 64;
    int r0 = c0 >> 2, cc0 = (c0 & 3) * 8;
    int r1 = c1 >> 2, cc1 = (c1 & 3) * 8;
    int tok0 = list[min(oe + gm + r0, oe + ce - 1)];
    int tok1 = list[min(oe + gm + r1, oe + ce - 1)];
    const u16* ag0 = xnp + (size_t)tok0 * K + cc0;
    const u16* ag1 = xnp + (size_t)tok1 * K + cc1;
    const u16* B1 = w1 + (size_t)e * FF * H;
    const u16* B3 = w3 + (size_t)e * FF * H;
    const u16* b1g0 = B1 + (size_t)(gn + r0) * K + cc0;
    const u16* b1g1 = B1 + (size_t)(gn + r1) * K + cc1;
    const u16* b3g0 = B3 + (size_t)(gn + r0) * K + cc0;
    const u16* b3g1 = B3 + (size_t)(gn + r1) * K + cc1;
    u16* la0 = As + (size_t)(wv * 128) * 8;
    u16* la1 = As + (size_t)(wv * 128 + 64) * 8;
    u16* l10 = B1s + (size_t)(wv * 128) * 8;
    u16* l11 = B1s + (size_t)(wv * 128 + 64) * 8;
    u16* l30 = B3s + (size_t)(wv * 128) * 8;
    u16* l31 = B3s + (size_t)(wv * 128 + 64) * 8;
    int am = (wv >> 1) * 64, bn = (wv & 1) * 64;
    f32x4 a1[4][4], a3[4][4];
#pragma unroll
    for (int i = 0; i < 4; i++)
#pragma unroll
        for (int j = 0; j < 4; j++) {
            a1[i][j] = (f32x4){0.f, 0.f, 0.f, 0.f};
            a3[i][j] = (f32x4){0.f, 0.f, 0.f, 0.f};
        }
    for (int kk = 0; kk < K; kk += 32) {
        gll16(ag0 + kk, la0);
        gll16(ag1 + kk, la1);
        gll16(b1g0 + kk, l10);
        gll16(b1g1 + kk, l11);
        gll16(b3g0 + kk, l30);
        gll16(b3g1 + kk, l31);
        __syncthreads();
        bf16x8 a[4], b1v[4], b3v[4];
#pragma unroll
        for (int i = 0; i < 4; i++) a[i] = *(const bf16x8*)(As + (am + i * 16 + l15) * 32 + quad * 8);
#pragma unroll
        for (int j = 0; j < 4; j++) {
            b1v[j] = *(const bf16x8*)(B1s + (bn + j * 16 + l15) * 32 + quad * 8);
            b3v[j] = *(const bf16x8*)(B3s + (bn + j * 16 + l15) * 32 + quad * 8);
        }
#pragma unroll
        for (int i = 0; i < 4; i++)
#pragma unroll
            for (int j = 0; j < 4; j++) {
                a1[i][j] = MFMA(a[i], b1v[j], a1[i][j]);
                a3[i][j] = MFMA(a[i], b3v[j], a3[i][j]);
            }
        __syncthreads();
    }
#pragma unroll
    for (int i = 0; i < 4; i++) {
        int rb = gm + am + i * 16 + quad * 4;
#pragma unroll
        for (int r = 0; r < 4; r++) {
            int row = rb + r;
            if (row < ce) {
#pragma unroll
                for (int j = 0; j < 4; j++) {
                    int col = gn + bn + j * 16 + l15;
                    float h1 = a1[i][j][r], h3 = a3[i][j][r];
                    float sv = h1 / (1.0f + __expf(-h1));
                    act[(size_t)(oe + row) * FF + col] = f2b(sv * h3);
                }
            }
        }
    }
}

// ---------------- staged expert GEMM2: y = act @ w2^T (slot rows, K=2048,N=1024) ----------------
__global__ __launch_bounds__(256) void k_gemm2(const u16* __restrict__ act,
                                               const u16* __restrict__ w2,
                                               const int* __restrict__ cnt,
                                               const int* __restrict__ offs,
                                               float* __restrict__ y) {
    int e = blockIdx.z;
    int ce = cnt[e], oe = offs[e];
    int gm = blockIdx.y * 128;
    if (gm >= ce) return;
    __shared__ u16 As[128 * 32], Bs[128 * 32];
    const int K = FF;
    int lane = threadIdx.x & 63, wv = threadIdx.x >> 6;
    int l15 = lane & 15, quad = lane >> 4;
    int gn = blockIdx.x * 128;
    int c0 = wv * 128 + lane, c1 = c0 + 64;
    int r0 = c0 >> 2, cc0 = (c0 & 3) * 8;
    int r1 = c1 >> 2, cc1 = (c1 & 3) * 8;
    int sr0 = min(oe + gm + r0, oe + ce - 1);
    int sr1 = min(oe + gm + r1, oe + ce - 1);
    const u16* ag0 = act + (size_t)sr0 * K + cc0;
    const u16* ag1 = act + (size_t)sr1 * K + cc1;
    const u16* B = w2 + (size_t)e * H * FF;
    const u16* bg0 = B + (size_t)(gn + r0) * K + cc0;
    const u16* bg1 = B + (size_t)(gn + r1) * K + cc1;
    u16* la0 = As + (size_t)(wv * 128) * 8;
    u16* la1 = As + (size_t)(wv * 128 + 64) * 8;
    u16* lb0 = Bs + (size_t)(wv * 128) * 8;
    u16* lb1 = Bs + (size_t)(wv * 128 + 64) * 8;
    int am = (wv >> 1) * 64, bn = (wv & 1) * 64;
    f32x4 acc[4][4];
#pragma unroll
    for (int i = 0; i < 4; i++)
#pragma unroll
        for (int j = 0; j < 4; j++) acc[i][j] = (f32x4){0.f, 0.f, 0.f, 0.f};
    for (int kk = 0; kk < K; kk += 32) {
        gll16(ag0 + kk, la0);
        gll16(ag1 + kk, la1);
        gll16(bg0 + kk, lb0);
        gll16(bg1 + kk, lb1);
        __syncthreads();
        bf16x8 a[4], b[4];
#pragma unroll
        for (int i = 0; i < 4; i++) a[i] = *(const bf16x8*)(As + (am + i * 16 + l15) * 32 + quad * 8);
#pragma unroll
        for (int j = 0; j < 4; j++) b[j] = *(const bf16x8*)(Bs + (bn + j * 16 + l15) * 32 + quad * 8);
#pragma unroll
        for (int i = 0; i < 4; i++)
#pragma unroll
            for (int j = 0; j < 4; j++) acc[i][j] = MFMA(a[i], b[j], acc[i][j]);
        __syncthreads();
    }
#pragma unroll
    for (int i = 0; i < 4; i++) {
        int rb = gm + am + i * 16 + quad * 4;
#pragma unroll
        for (int r = 0; r < 4; r++) {
            int row = rb + r;
            if (row < ce) {
#pragma unroll
                for (int j = 0; j < 4; j++) {
                    int col = gn + bn + j * 16 + l15;
                    y[(size_t)(oe + row) * H + col] = acc[i][j][r];
                }
            }
        }
    }
}

// ---------------- combine + final rmsnorm, write both outputs (f32) ----------------
__global__ __launch_bounds__(256) void k_combine(const float* __restrict__ x1,
                                                 const float* __restrict__ y,
                                                 const int* __restrict__ slotof,
                                                 const float* __restrict__ gwt,
                                                 const float* __restrict__ wnext,
                                                 float* __restrict__ dout) {
    int t = blockIdx.x;
    int s0 = slotof[2 * t], s1 = slotof[2 * t + 1];
    float g0 = gwt[2 * t], g1 = gwt[2 * t + 1];
    int base = threadIdx.x * 4;
    float v[4]; float ss = 0.f;
#pragma unroll
    for (int i = 0; i < 4; i++) {
        int idx = base + i;
        float val = x1[(size_t)t * H + idx] + g0 * y[(size_t)s0 * H + idx] + g1 * y[(size_t)s1 * H + idx];
        v[i] = val; ss += val * val;
    }
#pragma unroll
    for (int off = 32; off; off >>= 1) ss += __shfl_xor(ss, off, 64);
    __shared__ float red[4];
    int wv = threadIdx.x >> 6, lane = threadIdx.x & 63;
    if (lane == 0) red[wv] = ss;
    __syncthreads();
    float tot = red[0] + red[1] + red[2] + red[3];
    float s = rsqrtf(tot * (1.0f / H) + 1e-5f);
#pragma unroll
    for (int i = 0; i < 4; i++) {
        int idx = base + i;
        dout[(size_t)t * H + idx] = v[i] * s * wnext[idx];
        dout[(size_t)T * H + (size_t)t * H + idx] = v[i];
    }
}

extern "C" void kernel_launch(void* const* d_in, const int* in_sizes, int n_in,
                              void* d_out, int out_size, void* d_ws, size_t ws_size,
                              hipStream_t stream) {
    (void)in_sizes; (void)n_in; (void)out_size; (void)ws_size;
    const int*   positions = (const int*)d_in[0];
    const float* hidden    = (const float*)d_in[1];
    const float* w_qkv     = (const float*)d_in[2];
    const float* w_o       = (const float*)d_in[3];
    const float* norm_in   = (const float*)d_in[4];
    const float* norm_post = (const float*)d_in[5];
    const float* norm_next = (const float*)d_in[6];
    const float* gate_w    = (const float*)d_in[7];
    const float* w1        = (const float*)d_in[8];
    const float* w2        = (const float*)d_in[9];
    const float* w3        = (const float*)d_in[10];

    char* ws = (char*)d_ws;
    const size_t MB = (size_t)1 << 20;
    u16*   wqb  = (u16*)(ws + 0 * MB);     // 3 MB
    u16*   wob  = (u16*)(ws + 3 * MB);     // 2 MB
    u16*   w1b  = (u16*)(ws + 5 * MB);     // 32 MB
    u16*   w2b  = (u16*)(ws + 37 * MB);    // 32 MB
    u16*   w3b  = (u16*)(ws + 69 * MB);    // 32 MB
    u16*   xn_in= (u16*)(ws + 101 * MB);   // 4 MB
    float* qkv  = (float*)(ws + 105 * MB); // 12 MB (dead after rope)
    u16*   qb   = (u16*)(ws + 117 * MB);   // 4 MB
    u16*   kbuf = (u16*)(ws + 121 * MB);   // 1 MB
    u16*   vt   = (u16*)(ws + 122 * MB);   // 1 MB
    u16*   obuf = (u16*)(ws + 123 * MB);   // 4 MB
    float* x1   = (float*)(ws + 127 * MB); // 8 MB live to end
    u16*   xnp  = (u16*)(ws + 101 * MB);   // reuse xn_in slot
    u16*   act  = (u16*)(ws + 105 * MB);   // 16 MB reuse qkv/qb
    float* yb   = (float*)(ws + 135 * MB); // 16 MB
    char*  rt   = ws + 151 * MB;
    int*   cnt    = (int*)(rt);
    int*   offs   = (int*)(rt + 64);
    int*   ids    = (int*)(rt + 128);
    int*   rank   = (int*)(rt + 128 + 16384);
    float* gwt    = (float*)(rt + 128 + 2 * 16384);
    int*   slotof = (int*)(rt + 128 + 3 * 16384);
    int*   list   = (int*)(rt + 128 + 4 * 16384);
    float* dout   = (float*)d_out;

    k_cvt<<<dim3(QKVD * H / 2048), dim3(256), 0, stream>>>(w_qkv, wqb);
    k_cvt<<<dim3(H * H / 2048), dim3(256), 0, stream>>>(w_o, wob);
    k_cvt<<<dim3(NE * FF * H / 2048), dim3(256), 0, stream>>>(w1, w1b);
    k_cvt<<<dim3(NE * H * FF / 2048), dim3(256), 0, stream>>>(w2, w2b);
    k_cvt<<<dim3(NE * FF * H / 2048), dim3(256), 0, stream>>>(w3, w3b);

    k_rmsnorm<<<dim3(T), dim3(256), 0, stream>>>(hidden, norm_in, xn_in);
    k_gemm_qkv<<<dim3(QKVD / 128, T / 128), dim3(256), 0, stream>>>(xn_in, wqb, qkv);
    k_rope<<<dim3(T), dim3(256), 0, stream>>>(positions, qkv, qb, kbuf, vt);
    k_attn<<<dim3(T / 64, NH), dim3(256), 0, stream>>>(qb, kbuf, vt, obuf);
    k_gemm_wo<<<dim3(H / 128, T / 128), dim3(256), 0, stream>>>(obuf, wob, hidden, x1);
    k_rmsnorm<<<dim3(T), dim3(256), 0, stream>>>(x1, norm_post, xnp);
    k_zero<<<dim3(1), dim3(64), 0, stream>>>(cnt);
    k_route<<<dim3(T / 4), dim3(256), 0, stream>>>(x1, norm_post, gate_w, cnt, ids, rank, gwt);
    k_prefix<<<dim3(1), dim3(1), 0, stream>>>(cnt, offs);
    k_scatter<<<dim3(T / 256), dim3(256), 0, stream>>>(ids, rank, offs, list, slotof);
    k_gemm1<<<dim3(FF / 128, T / 128, NE), dim3(256), 0, stream>>>(xnp, w1b, w3b, cnt, offs, list, act);
    k_gemm2<<<dim3(H / 128, T / 128, NE), dim3(256), 0, stream>>>(act, w2b, cnt, offs, yb);
    k_combine<<<dim3(T), dim3(256), 0, stream>>>(x1, yb, slotof, gwt, norm_next, dout);
}

// Round 6
// 597.255 us; speedup vs baseline: 1.3776x; 1.0601x over previous
//
#include <hip/hip_runtime.h>
#include <hip/hip_bf16.h>
#include <stdint.h>

#define T 2048
#define H 1024
#define NH 16
#define NKV 4
#define HD 64
#define NE 8
#define FF 2048
#define QKVD 1536

typedef unsigned short u16;
typedef short bf16x8 __attribute__((ext_vector_type(8)));
typedef float f32x4 __attribute__((ext_vector_type(4)));

__device__ __forceinline__ float bf2f(u16 u) { return __uint_as_float(((unsigned)u) << 16); }
__device__ __forceinline__ u16 f2b(float f) {
    unsigned u = __float_as_uint(f);
    unsigned r = (u + 0x7FFFu + ((u >> 16) & 1u)) >> 16;
    return (u16)r;
}

#define MFMA(a, b, c) __builtin_amdgcn_mfma_f32_16x16x32_bf16(a, b, c, 0, 0, 0)

// async global->LDS, 16B per lane; LDS dest = wave-uniform base + lane*16
__device__ __forceinline__ void gll16(const u16* g, u16* l) {
    __builtin_amdgcn_global_load_lds(
        (const __attribute__((address_space(1))) void*)g,
        (__attribute__((address_space(3))) void*)l, 16, 0, 0);
}

// ---------------- f32 -> bf16 convert ----------------
__device__ __forceinline__ void cvt_body(const float* __restrict__ src,
                                         u16* __restrict__ dst) {
    size_t i = ((size_t)blockIdx.x * 256 + threadIdx.x) * 8;
    float4 a = *(const float4*)(src + i);
    float4 b = *(const float4*)(src + i + 4);
    bf16x8 o;
    o[0] = (short)f2b(a.x); o[1] = (short)f2b(a.y);
    o[2] = (short)f2b(a.z); o[3] = (short)f2b(a.w);
    o[4] = (short)f2b(b.x); o[5] = (short)f2b(b.y);
    o[6] = (short)f2b(b.z); o[7] = (short)f2b(b.w);
    *(bf16x8*)(dst + i) = o;
}

__global__ __launch_bounds__(256) void k_cvt(const float* __restrict__ src,
                                             u16* __restrict__ dst) {
    cvt_body(src, dst);
}

__global__ __launch_bounds__(256) void k_cvt3(const float* __restrict__ s0, u16* __restrict__ d0,
                                              const float* __restrict__ s1, u16* __restrict__ d1,
                                              const float* __restrict__ s2, u16* __restrict__ d2) {
    const float* s; u16* d;
    if (blockIdx.y == 0) { s = s0; d = d0; }
    else if (blockIdx.y == 1) { s = s1; d = d1; }
    else { s = s2; d = d2; }
    cvt_body(s, d);
}

// ---------------- rmsnorm (f32 in, bf16 out) ----------------
__global__ __launch_bounds__(256) void k_rmsnorm(const float* __restrict__ x,
                                                 const float* __restrict__ w,
                                                 u16* __restrict__ out) {
    int t = blockIdx.x;
    const float* xr = x + (size_t)t * H;
    int base = threadIdx.x * 4;
    float v[4]; float ss = 0.f;
#pragma unroll
    for (int i = 0; i < 4; i++) { v[i] = xr[base + i]; ss += v[i] * v[i]; }
#pragma unroll
    for (int off = 32; off; off >>= 1) ss += __shfl_xor(ss, off, 64);
    __shared__ float red[4];
    int wv = threadIdx.x >> 6, lane = threadIdx.x & 63;
    if (lane == 0) red[wv] = ss;
    __syncthreads();
    float tot = red[0] + red[1] + red[2] + red[3];
    float s = rsqrtf(tot * (1.0f / H) + 1e-5f);
    u16* orow = out + (size_t)t * H;
#pragma unroll
    for (int i = 0; i < 4; i++) orow[base + i] = f2b(v[i] * s * w[base + i]);
}

// ---------------- staged GEMM: qkv = xn_in @ w_qkv^T (M=2048,N=1536,K=1024) ----------------
__global__ __launch_bounds__(256) void k_gemm_qkv(const u16* __restrict__ A,
                                                  const u16* __restrict__ B,
                                                  float* __restrict__ C) {
    __shared__ u16 As[128 * 32], Bs[128 * 32];
    const int K = H;
    int lane = threadIdx.x & 63, wv = threadIdx.x >> 6;
    int l15 = lane & 15, quad = lane >> 4;
    int gm = blockIdx.y * 128, gn = blockIdx.x * 128;
    int c0 = wv * 128 + lane, c1 = c0 + 64;
    int r0 = c0 >> 2, cc0 = (c0 & 3) * 8;
    int r1 = c1 >> 2, cc1 = (c1 & 3) * 8;
    const u16* ag0 = A + (size_t)(gm + r0) * K + cc0;
    const u16* ag1 = A + (size_t)(gm + r1) * K + cc1;
    const u16* bg0 = B + (size_t)(gn + r0) * K + cc0;
    const u16* bg1 = B + (size_t)(gn + r1) * K + cc1;
    u16* la0 = As + (size_t)(wv * 128) * 8;
    u16* la1 = As + (size_t)(wv * 128 + 64) * 8;
    u16* lb0 = Bs + (size_t)(wv * 128) * 8;
    u16* lb1 = Bs + (size_t)(wv * 128 + 64) * 8;
    int am = (wv >> 1) * 64, bn = (wv & 1) * 64;
    f32x4 acc[4][4];
#pragma unroll
    for (int i = 0; i < 4; i++)
#pragma unroll
        for (int j = 0; j < 4; j++) acc[i][j] = (f32x4){0.f, 0.f, 0.f, 0.f};
    for (int kk = 0; kk < K; kk += 32) {
        gll16(ag0 + kk, la0);
        gll16(ag1 + kk, la1);
        gll16(bg0 + kk, lb0);
        gll16(bg1 + kk, lb1);
        __syncthreads();
        bf16x8 a[4], b[4];
#pragma unroll
        for (int i = 0; i < 4; i++) a[i] = *(const bf16x8*)(As + (am + i * 16 + l15) * 32 + quad * 8);
#pragma unroll
        for (int j = 0; j < 4; j++) b[j] = *(const bf16x8*)(Bs + (bn + j * 16 + l15) * 32 + quad * 8);
#pragma unroll
        for (int i = 0; i < 4; i++)
#pragma unroll
            for (int j = 0; j < 4; j++) acc[i][j] = MFMA(a[i], b[j], acc[i][j]);
        __syncthreads();
    }
#pragma unroll
    for (int i = 0; i < 4; i++) {
        int row = gm + am + i * 16 + quad * 4;
#pragma unroll
        for (int j = 0; j < 4; j++) {
            int col = gn + bn + j * 16 + l15;
#pragma unroll
            for (int r = 0; r < 4; r++) C[(size_t)(row + r) * QKVD + col] = acc[i][j][r];
        }
    }
}

// ---------------- RoPE + repack to bf16 (V transposed) ----------------
__global__ __launch_bounds__(256) void k_rope(const int* __restrict__ positions,
                                              const float* __restrict__ qkv,
                                              u16* __restrict__ qb, u16* __restrict__ kb,
                                              u16* __restrict__ vt) {
    int t = blockIdx.x;
    float p = (float)positions[t];
    const float* base = qkv + (size_t)t * QKVD;
    const float kfreq = -9.210340371976184f / 32.0f;  // -ln(10000)/half
    for (int idx = threadIdx.x; idx < 512; idx += 256) {
        int hh = idx >> 5, d = idx & 31;
        float ang = p * __expf((float)d * kfreq);
        float cs = cosf(ang), sn = sinf(ang);
        float x1 = base[hh * 64 + d], x2 = base[hh * 64 + d + 32];
        qb[(size_t)t * 1024 + hh * 64 + d] = f2b(x1 * cs - x2 * sn);
        qb[(size_t)t * 1024 + hh * 64 + d + 32] = f2b(x2 * cs + x1 * sn);
    }
    if (threadIdx.x < 128) {
        int idx = threadIdx.x, kh = idx >> 5, d = idx & 31;
        float ang = p * __expf((float)d * kfreq);
        float cs = cosf(ang), sn = sinf(ang);
        const float* kin = base + 1024;
        float x1 = kin[kh * 64 + d], x2 = kin[kh * 64 + d + 32];
        kb[((size_t)t * NKV + kh) * 64 + d] = f2b(x1 * cs - x2 * sn);
        kb[((size_t)t * NKV + kh) * 64 + d + 32] = f2b(x2 * cs + x1 * sn);
    }
    {
        int idx = threadIdx.x;
        vt[(size_t)idx * T + t] = f2b(base[1280 + idx]);
    }
}

// ---------------- flash attention (causal, GQA 4:1), KV-tile=64, no barriers ----------------
__global__ __launch_bounds__(256) void k_attn(const u16* __restrict__ qb,
                                              const u16* __restrict__ kb,
                                              const u16* __restrict__ vt,
                                              u16* __restrict__ o) {
    // complementary-pair swizzle: blocks g and g+256 (co-resident) get q-tiles qt and 31-qt
    int g = blockIdx.x;
    int pair = g & 255, sel = g >> 8;
    int h = pair & 15, qt = pair >> 4;
    int qtile = sel ? (31 - qt) : qt;
    int q0 = qtile * 64;
    int kh = h >> 2;
    int wv = threadIdx.x >> 6, lane = threadIdx.x & 63;
    int l15 = lane & 15, quad = lane >> 4;
    int qw = q0 + wv * 16;
    __shared__ __align__(16) u16 pl[4][16 * 64];   // per-wave P buffer -> NO barriers
    u16* plw = pl[wv];
    const f32x4 zero4 = {0.f, 0.f, 0.f, 0.f};

    const u16* qrow = qb + (size_t)(qw + l15) * 1024 + h * 64 + quad * 8;
    bf16x8 aq0 = *(const bf16x8*)qrow;
    bf16x8 aq1 = *(const bf16x8*)(qrow + 32);

    const u16* kbase = kb + kh * 64 + quad * 8;
    const u16* vbase = vt + (size_t)(kh * 64) * T + quad * 8;

    f32x4 oacc[4];
#pragma unroll
    for (int c = 0; c < 4; c++) oacc[c] = zero4;
    float mi[4], li[4];
#pragma unroll
    for (int r = 0; r < 4; r++) { mi[r] = -3e38f; li[r] = 0.f; }

    int ntiles = qtile + 1;
    for (int ti = 0; ti < ntiles; ++ti) {
        int kv0 = ti * 64;
        f32x4 sC[4];
#pragma unroll
        for (int c = 0; c < 4; c++) {
            const u16* kr = kbase + (size_t)(kv0 + c * 16 + l15) * (NKV * 64);
            sC[c] = MFMA(aq0, *(const bf16x8*)kr, zero4);
            sC[c] = MFMA(aq1, *(const bf16x8*)(kr + 32), sC[c]);
        }
#pragma unroll
        for (int r = 0; r < 4; r++) {
            int qi = qw + quad * 4 + r;
            float sc[4];
#pragma unroll
            for (int c = 0; c < 4; c++) {
                int col = kv0 + c * 16 + l15;
                sc[c] = (col <= qi) ? sC[c][r] * 0.125f : -3e38f;
            }
            float mx = fmaxf(fmaxf(sc[0], sc[1]), fmaxf(sc[2], sc[3]));
#pragma unroll
            for (int off = 1; off < 16; off <<= 1) mx = fmaxf(mx, __shfl_xor(mx, off, 64));
            float mn = fmaxf(mi[r], mx);
            float alpha = __expf(mi[r] - mn);
            float p0 = __expf(sc[0] - mn), p1 = __expf(sc[1] - mn);
            float p2 = __expf(sc[2] - mn), p3 = __expf(sc[3] - mn);
            float ps = (p0 + p1) + (p2 + p3);
#pragma unroll
            for (int off = 1; off < 16; off <<= 1) ps += __shfl_xor(ps, off, 64);
            li[r] = li[r] * alpha + ps;
            mi[r] = mn;
#pragma unroll
            for (int c = 0; c < 4; c++) oacc[c][r] *= alpha;
            int prow = quad * 4 + r;
            plw[prow * 64 + l15] = f2b(p0);
            plw[prow * 64 + 16 + l15] = f2b(p1);
            plw[prow * 64 + 32 + l15] = f2b(p2);
            plw[prow * 64 + 48 + l15] = f2b(p3);
        }
        bf16x8 pf0 = *(const bf16x8*)&plw[l15 * 64 + quad * 8];
        bf16x8 pf1 = *(const bf16x8*)&plw[l15 * 64 + 32 + quad * 8];
#pragma unroll
        for (int c = 0; c < 4; c++) {
            const u16* vr = vbase + (size_t)(c * 16 + l15) * T + kv0;
            oacc[c] = MFMA(pf0, *(const bf16x8*)vr, oacc[c]);
            oacc[c] = MFMA(pf1, *(const bf16x8*)(vr + 32), oacc[c]);
        }
    }
#pragma unroll
    for (int r = 0; r < 4; r++) {
        float inv = 1.0f / li[r];
        int row = qw + quad * 4 + r;
#pragma unroll
        for (int c = 0; c < 4; c++)
            o[(size_t)row * 1024 + h * 64 + c * 16 + l15] = f2b(oacc[c][r] * inv);
    }
}

// ---------------- staged GEMM: x1 = hidden + o @ w_o^T (M=2048,N=1024,K=1024) ----------------
__global__ __launch_bounds__(256) void k_gemm_wo(const u16* __restrict__ A,
                                                 const u16* __restrict__ B,
                                                 const float* __restrict__ hid,
                                                 float* __restrict__ x1) {
    __shared__ u16 As[128 * 32], Bs[128 * 32];
    const int K = H;
    int lane = threadIdx.x & 63, wv = threadIdx.x >> 6;
    int l15 = lane & 15, quad = lane >> 4;
    int gm = blockIdx.y * 128, gn = blockIdx.x * 128;
    int c0 = wv * 128 + lane, c1 = c0 + 64;
    int r0 = c0 >> 2, cc0 = (c0 & 3) * 8;
    int r1 = c1 >> 2, cc1 = (c1 & 3) * 8;
    const u16* ag0 = A + (size_t)(gm + r0) * K + cc0;
    const u16* ag1 = A + (size_t)(gm + r1) * K + cc1;
    const u16* bg0 = B + (size_t)(gn + r0) * K + cc0;
    const u16* bg1 = B + (size_t)(gn + r1) * K + cc1;
    u16* la0 = As + (size_t)(wv * 128) * 8;
    u16* la1 = As + (size_t)(wv * 128 + 64) * 8;
    u16* lb0 = Bs + (size_t)(wv * 128) * 8;
    u16* lb1 = Bs + (size_t)(wv * 128 + 64) * 8;
    int am = (wv >> 1) * 64, bn = (wv & 1) * 64;
    f32x4 acc[4][4];
#pragma unroll
    for (int i = 0; i < 4; i++)
#pragma unroll
        for (int j = 0; j < 4; j++) acc[i][j] = (f32x4){0.f, 0.f, 0.f, 0.f};
    for (int kk = 0; kk < K; kk += 32) {
        gll16(ag0 + kk, la0);
        gll16(ag1 + kk, la1);
        gll16(bg0 + kk, lb0);
        gll16(bg1 + kk, lb1);
        __syncthreads();
        bf16x8 a[4], b[4];
#pragma unroll
        for (int i = 0; i < 4; i++) a[i] = *(const bf16x8*)(As + (am + i * 16 + l15) * 32 + quad * 8);
#pragma unroll
        for (int j = 0; j < 4; j++) b[j] = *(const bf16x8*)(Bs + (bn + j * 16 + l15) * 32 + quad * 8);
#pragma unroll
        for (int i = 0; i < 4; i++)
#pragma unroll
            for (int j = 0; j < 4; j++) acc[i][j] = MFMA(a[i], b[j], acc[i][j]);
        __syncthreads();
    }
#pragma unroll
    for (int i = 0; i < 4; i++) {
        int row = gm + am + i * 16 + quad * 4;
#pragma unroll
        for (int j = 0; j < 4; j++) {
            int col = gn + bn + j * 16 + l15;
#pragma unroll
            for (int r = 0; r < 4; r++) {
                size_t idx = (size_t)(row + r) * H + col;
                x1[idx] = hid[idx] + acc[i][j][r];
            }
        }
    }
}

// ---------------- MoE routing (full f32: matches np reference) ----------------
__global__ void k_zero(int* cnt) { if (threadIdx.x < NE) cnt[threadIdx.x] = 0; }

__global__ __launch_bounds__(256) void k_route(const float* __restrict__ x1,
                                               const float* __restrict__ wpost,
                                               const float* __restrict__ gw,
                                               int* cnt, int* ids, int* rank,
                                               float* gwt) {
    int wv = threadIdx.x >> 6, lane = threadIdx.x & 63;
    int t = blockIdx.x * 4 + wv;
    const float* xr = x1 + (size_t)t * H + lane * 16;
    float pv[16];
    float ss = 0.f;
#pragma unroll
    for (int i = 0; i < 16; i++) { float v = xr[i]; pv[i] = v; ss += v * v; }
#pragma unroll
    for (int off = 32; off; off >>= 1) ss += __shfl_xor(ss, off, 64);
    float s = rsqrtf(ss * (1.0f / H) + 1e-5f);
#pragma unroll
    for (int i = 0; i < 16; i++) pv[i] *= wpost[lane * 16 + i];
    float lg[NE];
#pragma unroll
    for (int e = 0; e < NE; e++) {
        const float* gr = gw + (size_t)e * H + lane * 16;
        float d = 0.f;
#pragma unroll
        for (int i = 0; i < 16; i++) d += pv[i] * gr[i];
#pragma unroll
        for (int off = 32; off; off >>= 1) d += __shfl_xor(d, off, 64);
        lg[e] = d * s;
    }
    if (lane == 0) {
        int i0 = 0; float b0 = lg[0];
        for (int e = 1; e < NE; e++) if (lg[e] > b0) { b0 = lg[e]; i0 = e; }
        int i1 = (i0 == 0) ? 1 : 0; float b1 = lg[i1];
        for (int e = 0; e < NE; e++)
            if (e != i0 && lg[e] > b1) { b1 = lg[e]; i1 = e; }
        float g0 = 1.0f / (1.0f + __expf(b1 - b0));
        float g1 = 1.0f - g0;
        int r0 = atomicAdd(&cnt[i0], 1);
        int r1 = atomicAdd(&cnt[i1], 1);
        ids[2 * t] = i0; ids[2 * t + 1] = i1;
        rank[2 * t] = r0; rank[2 * t + 1] = r1;
        gwt[2 * t] = g0; gwt[2 * t + 1] = g1;
    }
}

__global__ void k_prefix(const int* cnt, int* offs) {
    if (threadIdx.x == 0) {
        int a = 0;
        for (int e = 0; e < NE; e++) { offs[e] = a; a += cnt[e]; }
    }
}

__global__ __launch_bounds__(256) void k_scatter(const int* __restrict__ ids,
                                                 const int* __restrict__ rank,
                                                 const int* __restrict__ offs,
                                                 int* __restrict__ list,
                                                 int* __restrict__ slotof) {
    int t = blockIdx.x * 256 + threadIdx.x;
#pragma unroll
    for (int j = 0; j < 2; j++) {
        int e = ids[2 * t + j];
        int s = offs[e] + rank[2 * t + j];
        list[s] = t;
        slotof[2 * t + j] = s;
    }
}

// ---------------- staged expert GEMM1: act = silu(x@w1^T)*(x@w3^T), gathered A ----------------
__global__ __launch_bounds__(256, 2) void k_gemm1(const u16* __restrict__ xnp,
                                                  const u16* __restrict__ w1,
                                                  const u16* __restrict__ w3,
                                                  const int* __restrict__ cnt,
                                                  const int* __restrict__ offs,
                                                  const int* __restrict__ list,
                                                  u16* __restrict__ act) {
    int e = blockIdx.z;
    int ce = cnt[e], oe = offs[e];
    int gm = blockIdx.y * 128;
    if (gm >= ce) return;
    __shared__ u16 As[128 * 32], B1s[128 * 32], B3s[128 * 32];
    const int K = H;
    int lane = threadIdx.x & 63, wv = threadIdx.x >> 6;
    int l15 = lane & 15, quad = lane >> 4;
    int gn = blockIdx.x * 128;
    int c0 = wv * 128 + lane, c1 = c0 + 64;
    int r0 = c0 >> 2, cc0 = (c0 & 3) * 8;
    int r1 = c1 >> 2, cc1 = (c1 & 3) * 8;
    int tok0 = list[min(oe + gm + r0, oe + ce - 1)];
    int tok1 = list[min(oe + gm + r1, oe + ce - 1)];
    const u16* ag0 = xnp + (size_t)tok0 * K + cc0;
    const u16* ag1 = xnp + (size_t)tok1 * K + cc1;
    const u16* B1 = w1 + (size_t)e * FF * H;
    const u16* B3 = w3 + (size_t)e * FF * H;
    const u16* b1g0 = B1 + (size_t)(gn + r0) * K + cc0;
    const u16* b1g1 = B1 + (size_t)(gn + r1) * K + cc1;
    const u16* b3g0 = B3 + (size_t)(gn + r0) * K + cc0;
    const u16* b3g1 = B3 + (size_t)(gn + r1) * K + cc1;
    u16* la0 = As + (size_t)(wv * 128) * 8;
    u16* la1 = As + (size_t)(wv * 128 + 64) * 8;
    u16* l10 = B1s + (size_t)(wv * 128) * 8;
    u16* l11 = B1s + (size_t)(wv * 128 + 64) * 8;
    u16* l30 = B3s + (size_t)(wv * 128) * 8;
    u16* l31 = B3s + (size_t)(wv * 128 + 64) * 8;
    int am = (wv >> 1) * 64, bn = (wv & 1) * 64;
    f32x4 a1[4][4], a3[4][4];
#pragma unroll
    for (int i = 0; i < 4; i++)
#pragma unroll
        for (int j = 0; j < 4; j++) {
            a1[i][j] = (f32x4){0.f, 0.f, 0.f, 0.f};
            a3[i][j] = (f32x4){0.f, 0.f, 0.f, 0.f};
        }
    for (int kk = 0; kk < K; kk += 32) {
        gll16(ag0 + kk, la0);
        gll16(ag1 + kk, la1);
        gll16(b1g0 + kk, l10);
        gll16(b1g1 + kk, l11);
        gll16(b3g0 + kk, l30);
        gll16(b3g1 + kk, l31);
        __syncthreads();
        bf16x8 a[4], b1v[4], b3v[4];
#pragma unroll
        for (int i = 0; i < 4; i++) a[i] = *(const bf16x8*)(As + (am + i * 16 + l15) * 32 + quad * 8);
#pragma unroll
        for (int j = 0; j < 4; j++) {
            b1v[j] = *(const bf16x8*)(B1s + (bn + j * 16 + l15) * 32 + quad * 8);
            b3v[j] = *(const bf16x8*)(B3s + (bn + j * 16 + l15) * 32 + quad * 8);
        }
#pragma unroll
        for (int i = 0; i < 4; i++)
#pragma unroll
            for (int j = 0; j < 4; j++) {
                a1[i][j] = MFMA(a[i], b1v[j], a1[i][j]);
                a3[i][j] = MFMA(a[i], b3v[j], a3[i][j]);
            }
        __syncthreads();
    }
#pragma unroll
    for (int i = 0; i < 4; i++) {
        int rb = gm + am + i * 16 + quad * 4;
#pragma unroll
        for (int r = 0; r < 4; r++) {
            int row = rb + r;
            if (row < ce) {
#pragma unroll
                for (int j = 0; j < 4; j++) {
                    int col = gn + bn + j * 16 + l15;
                    float h1 = a1[i][j][r], h3 = a3[i][j][r];
                    float sv = h1 / (1.0f + __expf(-h1));
                    act[(size_t)(oe + row) * FF + col] = f2b(sv * h3);
                }
            }
        }
    }
}

// ---------------- staged expert GEMM2: y = act @ w2^T (slot rows, K=2048,N=1024) ----------------
__global__ __launch_bounds__(256) void k_gemm2(const u16* __restrict__ act,
                                               const u16* __restrict__ w2,
                                               const int* __restrict__ cnt,
                                               const int* __restrict__ offs,
                                               float* __restrict__ y) {
    int e = blockIdx.z;
    int ce = cnt[e], oe = offs[e];
    int gm = blockIdx.y * 128;
    if (gm >= ce) return;
    __shared__ u16 As[128 * 32], Bs[128 * 32];
    const int K = FF;
    int lane = threadIdx.x & 63, wv = threadIdx.x >> 6;
    int l15 = lane & 15, quad = lane >> 4;
    int gn = blockIdx.x * 128;
    int c0 = wv * 128 + lane, c1 = c0 + 64;
    int r0 = c0 >> 2, cc0 = (c0 & 3) * 8;
    int r1 = c1 >> 2, cc1 = (c1 & 3) * 8;
    int sr0 = min(oe + gm + r0, oe + ce - 1);
    int sr1 = min(oe + gm + r1, oe + ce - 1);
    const u16* ag0 = act + (size_t)sr0 * K + cc0;
    const u16* ag1 = act + (size_t)sr1 * K + cc1;
    const u16* B = w2 + (size_t)e * H * FF;
    const u16* bg0 = B + (size_t)(gn + r0) * K + cc0;
    const u16* bg1 = B + (size_t)(gn + r1) * K + cc1;
    u16* la0 = As + (size_t)(wv * 128) * 8;
    u16* la1 = As + (size_t)(wv * 128 + 64) * 8;
    u16* lb0 = Bs + (size_t)(wv * 128) * 8;
    u16* lb1 = Bs + (size_t)(wv * 128 + 64) * 8;
    int am = (wv >> 1) * 64, bn = (wv & 1) * 64;
    f32x4 acc[4][4];
#pragma unroll
    for (int i = 0; i < 4; i++)
#pragma unroll
        for (int j = 0; j < 4; j++) acc[i][j] = (f32x4){0.f, 0.f, 0.f, 0.f};
    for (int kk = 0; kk < K; kk += 32) {
        gll16(ag0 + kk, la0);
        gll16(ag1 + kk, la1);
        gll16(bg0 + kk, lb0);
        gll16(bg1 + kk, lb1);
        __syncthreads();
        bf16x8 a[4], b[4];
#pragma unroll
        for (int i = 0; i < 4; i++) a[i] = *(const bf16x8*)(As + (am + i * 16 + l15) * 32 + quad * 8);
#pragma unroll
        for (int j = 0; j < 4; j++) b[j] = *(const bf16x8*)(Bs + (bn + j * 16 + l15) * 32 + quad * 8);
#pragma unroll
        for (int i = 0; i < 4; i++)
#pragma unroll
            for (int j = 0; j < 4; j++) acc[i][j] = MFMA(a[i], b[j], acc[i][j]);
        __syncthreads();
    }
#pragma unroll
    for (int i = 0; i < 4; i++) {
        int rb = gm + am + i * 16 + quad * 4;
#pragma unroll
        for (int r = 0; r < 4; r++) {
            int row = rb + r;
            if (row < ce) {
#pragma unroll
                for (int j = 0; j < 4; j++) {
                    int col = gn + bn + j * 16 + l15;
                    y[(size_t)(oe + row) * H + col] = acc[i][j][r];
                }
            }
        }
    }
}

// ---------------- combine + final rmsnorm, write both outputs (f32) ----------------
__global__ __launch_bounds__(256) void k_combine(const float* __restrict__ x1,
                                                 const float* __restrict__ y,
                                                 const int* __restrict__ slotof,
                                                 const float* __restrict__ gwt,
                                                 const float* __restrict__ wnext,
                                                 float* __restrict__ dout) {
    int t = blockIdx.x;
    int s0 = slotof[2 * t], s1 = slotof[2 * t + 1];
    float g0 = gwt[2 * t], g1 = gwt[2 * t + 1];
    int base = threadIdx.x * 4;
    float v[4]; float ss = 0.f;
#pragma unroll
    for (int i = 0; i < 4; i++) {
        int idx = base + i;
        float val = x1[(size_t)t * H + idx] + g0 * y[(size_t)s0 * H + idx] + g1 * y[(size_t)s1 * H + idx];
        v[i] = val; ss += val * val;
    }
#pragma unroll
    for (int off = 32; off; off >>= 1) ss += __shfl_xor(ss, off, 64);
    __shared__ float red[4];
    int wv = threadIdx.x >> 6, lane = threadIdx.x & 63;
    if (lane == 0) red[wv] = ss;
    __syncthreads();
    float tot = red[0] + red[1] + red[2] + red[3];
    float s = rsqrtf(tot * (1.0f / H) + 1e-5f);
#pragma unroll
    for (int i = 0; i < 4; i++) {
        int idx = base + i;
        dout[(size_t)t * H + idx] = v[i] * s * wnext[idx];
        dout[(size_t)T * H + (size_t)t * H + idx] = v[i];
    }
}

extern "C" void kernel_launch(void* const* d_in, const int* in_sizes, int n_in,
                              void* d_out, int out_size, void* d_ws, size_t ws_size,
                              hipStream_t stream) {
    (void)in_sizes; (void)n_in; (void)out_size; (void)ws_size;
    const int*   positions = (const int*)d_in[0];
    const float* hidden    = (const float*)d_in[1];
    const float* w_qkv     = (const float*)d_in[2];
    const float* w_o       = (const float*)d_in[3];
    const float* norm_in   = (const float*)d_in[4];
    const float* norm_post = (const float*)d_in[5];
    const float* norm_next = (const float*)d_in[6];
    const float* gate_w    = (const float*)d_in[7];
    const float* w1        = (const float*)d_in[8];
    const float* w2        = (const float*)d_in[9];
    const float* w3        = (const float*)d_in[10];

    char* ws = (char*)d_ws;
    const size_t MB = (size_t)1 << 20;
    u16*   wqb  = (u16*)(ws + 0 * MB);     // 3 MB
    u16*   wob  = (u16*)(ws + 3 * MB);     // 2 MB
    u16*   w1b  = (u16*)(ws + 5 * MB);     // 32 MB
    u16*   w2b  = (u16*)(ws + 37 * MB);    // 32 MB
    u16*   w3b  = (u16*)(ws + 69 * MB);    // 32 MB
    u16*   xn_in= (u16*)(ws + 101 * MB);   // 4 MB
    float* qkv  = (float*)(ws + 105 * MB); // 12 MB (dead after rope)
    u16*   qb   = (u16*)(ws + 117 * MB);   // 4 MB
    u16*   kbuf = (u16*)(ws + 121 * MB);   // 1 MB
    u16*   vt   = (u16*)(ws + 122 * MB);   // 1 MB
    u16*   obuf = (u16*)(ws + 123 * MB);   // 4 MB
    float* x1   = (float*)(ws + 127 * MB); // 8 MB live to end
    u16*   xnp  = (u16*)(ws + 101 * MB);   // reuse xn_in slot
    u16*   act  = (u16*)(ws + 105 * MB);   // 16 MB reuse qkv/qb
    float* yb   = (float*)(ws + 135 * MB); // 16 MB
    char*  rt   = ws + 151 * MB;
    int*   cnt    = (int*)(rt);
    int*   offs   = (int*)(rt + 64);
    int*   ids    = (int*)(rt + 128);
    int*   rank   = (int*)(rt + 128 + 16384);
    float* gwt    = (float*)(rt + 128 + 2 * 16384);
    int*   slotof = (int*)(rt + 128 + 3 * 16384);
    int*   list   = (int*)(rt + 128 + 4 * 16384);
    float* dout   = (float*)d_out;

    k_cvt<<<dim3(QKVD * H / 2048), dim3(256), 0, stream>>>(w_qkv, wqb);
    k_cvt<<<dim3(H * H / 2048), dim3(256), 0, stream>>>(w_o, wob);
    k_cvt3<<<dim3(NE * FF * H / 2048, 3), dim3(256), 0, stream>>>(w1, w1b, w2, w2b, w3, w3b);

    k_rmsnorm<<<dim3(T), dim3(256), 0, stream>>>(hidden, norm_in, xn_in);
    k_gemm_qkv<<<dim3(QKVD / 128, T / 128), dim3(256), 0, stream>>>(xn_in, wqb, qkv);
    k_rope<<<dim3(T), dim3(256), 0, stream>>>(positions, qkv, qb, kbuf, vt);
    k_attn<<<dim3(512), dim3(256), 0, stream>>>(qb, kbuf, vt, obuf);
    k_gemm_wo<<<dim3(H / 128, T / 128), dim3(256), 0, stream>>>(obuf, wob, hidden, x1);
    k_rmsnorm<<<dim3(T), dim3(256), 0, stream>>>(x1, norm_post, xnp);
    k_zero<<<dim3(1), dim3(64), 0, stream>>>(cnt);
    k_route<<<dim3(T / 4), dim3(256), 0, stream>>>(x1, norm_post, gate_w, cnt, ids, rank, gwt);
    k_prefix<<<dim3(1), dim3(1), 0, stream>>>(cnt, offs);
    k_scatter<<<dim3(T / 256), dim3(256), 0, stream>>>(ids, rank, offs, list, slotof);
    k_gemm1<<<dim3(FF / 128, T / 128, NE), dim3(256), 0, stream>>>(xnp, w1b, w3b, cnt, offs, list, act);
    k_gemm2<<<dim3(H / 128, T / 128, NE), dim3(256), 0, stream>>>(act, w2b, cnt, offs, yb);
    k_combine<<<dim3(T), dim3(256), 0, stream>>>(x1, yb, slotof, gwt, norm_next, dout);
}